// Round 2
// baseline (481.500 us; speedup 1.0000x reference)
//
#include <hip/hip_runtime.h>
#include <stdint.h>

// HardNegLoss: N=8192 rows, C=5000 classes.
// loss = [ sum_pos (softplus(x)-x) + sum_{top-k negatives by pred} softplus(x) ] / sum(target)
// k = min(3*pos, C-pos). Selection by value-threshold == reference's argsort ranks
// (all negatives outrank all positives in score; tied values contribute identically).

#define C_DIM 5000
#define C4_DIM 1250
#define BLK 256
#define CAP 5120          // can hold all C elements -> fallback always fits
#define CUTOFF 0.5f       // threshold is always >> 0.5 for this data; fallback guards anyway

__device__ __forceinline__ float sp_f(float x) {
    // softplus, overflow-safe
    return fmaxf(x, 0.0f) + log1pf(__expf(-fabsf(x)));
}
__device__ __forceinline__ uint32_t mono_u(float x) {
    // monotone float->uint mapping
    uint32_t b = __float_as_uint(x);
    return b ^ ((b & 0x80000000u) ? 0xFFFFFFFFu : 0x80000000u);
}
__device__ __forceinline__ float unmono_f(uint32_t u) {
    uint32_t b = (u & 0x80000000u) ? (u ^ 0x80000000u) : ~u;
    return __uint_as_float(b);
}
__device__ __forceinline__ int vbin_of(float x) {
    // linear value bins (width 1/64 starting at CUTOFF): spreads N(0,1) data across
    // bins so LDS histogram atomics have ~1-way conflicts (exponent-prefix would pile
    // ~30% of values into one bin). Monotone non-decreasing in x.
    int v = (int)((x - CUTOFF) * 64.0f);
    return v > 255 ? 255 : (v < 0 ? 0 : v);
}

// find crossing bin from a 256-bin histogram for the kp-th largest (bins high=large).
// writes s_sel[0]=bin, s_sel[1]=count strictly above that bin. wave 0 only.
__device__ __forceinline__ void find_bin(const unsigned int* hist, int kp, int tid, int* s_sel) {
    if (tid < 64) {
        int c0 = (int)hist[4 * tid + 0];
        int c1 = (int)hist[4 * tid + 1];
        int c2 = (int)hist[4 * tid + 2];
        int c3 = (int)hist[4 * tid + 3];
        int lsum = c0 + c1 + c2 + c3;
        int s = lsum;
        #pragma unroll
        for (int off = 1; off < 64; off <<= 1) {
            int o = __shfl_down(s, off);
            if (tid + off < 64) s += o;
        }
        int above = s - lsum;          // elements in lanes (bins) strictly above mine
        if (above < kp && kp <= s) {   // exactly one lane satisfies
            int b, ab;
            if (kp <= above + c3)                { b = 4 * tid + 3; ab = above; }
            else if (kp <= above + c3 + c2)      { b = 4 * tid + 2; ab = above + c3; }
            else if (kp <= above + c3 + c2 + c1) { b = 4 * tid + 1; ab = above + c3 + c2; }
            else                                 { b = 4 * tid;     ab = above + c3 + c2 + c1; }
            s_sel[0] = b;
            s_sel[1] = ab;
        }
    }
}

__global__ __launch_bounds__(BLK) void hardneg_kernel(
    const float* __restrict__ pred, const float* __restrict__ target,
    double* __restrict__ num_acc, float* __restrict__ den_acc)
{
    __shared__ uint32_t s_buf[CAP];     // staged monotone-uint candidate values
    __shared__ unsigned int hist[256];
    __shared__ float f_scr[4];
    __shared__ int i_scr[4];
    __shared__ int s_cnt;
    __shared__ int s_sel[2];

    const int tid = threadIdx.x;
    const int lane = tid & 63;
    const int row = blockIdx.x;
    const float4* pr4 = (const float4*)(pred + (size_t)row * C_DIM);
    const float4* tg4 = (const float4*)(target + (size_t)row * C_DIM);

    if (tid == 0) s_cnt = 0;
    __syncthreads();

    // ---- Pass A: single global read. pos count/loss + stage candidate negatives ----
    float pos_loss = 0.0f;
    int pos_cnt = 0;
    for (int i = tid; i < C4_DIM; i += BLK) {
        float4 p = pr4[i];
        float4 t = tg4[i];
        float px[4] = {p.x, p.y, p.z, p.w};
        float tx[4] = {t.x, t.y, t.z, t.w};
        #pragma unroll
        for (int j = 0; j < 4; ++j) {
            float x = px[j];
            bool ispos = (tx[j] != 0.0f);
            if (ispos) { pos_cnt++; pos_loss += sp_f(x) - x; }
            bool cand = (!ispos) && (x > CUTOFF);
            unsigned long long m = __ballot(cand);
            if (m) {
                int c = __popcll(m);
                int leader = __ffsll((unsigned long long)m) - 1;
                int base = 0;
                if (lane == leader) base = atomicAdd(&s_cnt, c);
                base = __shfl(base, leader);
                if (cand) {
                    int pfx = __popcll(m & ((1ull << lane) - 1ull));
                    s_buf[base + pfx] = mono_u(x);
                }
            }
        }
    }

    // block-reduce pos count
    int v = pos_cnt;
    #pragma unroll
    for (int off = 32; off; off >>= 1) v += __shfl_down(v, off);
    if (lane == 0) i_scr[tid >> 6] = v;
    __syncthreads();
    const int pos_total = i_scr[0] + i_scr[1] + i_scr[2] + i_scr[3];
    const int k = min(3 * pos_total, C_DIM - pos_total);
    int cnt = s_cnt;

    if (k == 0) return;   // pos==0 -> no mask, no denominator contribution (uniform exit)

    // ---- Fallback (provably never for this data, kept for correctness): stage rest ----
    if (k > cnt) {
        for (int i = tid; i < C4_DIM; i += BLK) {
            float4 p = pr4[i];
            float4 t = tg4[i];
            float px[4] = {p.x, p.y, p.z, p.w};
            float tx[4] = {t.x, t.y, t.z, t.w};
            #pragma unroll
            for (int j = 0; j < 4; ++j) {
                float x = px[j];
                bool cand = (tx[j] == 0.0f) && !(x > CUTOFF);
                unsigned long long m = __ballot(cand);
                if (m) {
                    int c = __popcll(m);
                    int leader = __ffsll((unsigned long long)m) - 1;
                    int base = 0;
                    if (lane == leader) base = atomicAdd(&s_cnt, c);
                    base = __shfl(base, leader);
                    if (cand) {
                        int pfx = __popcll(m & ((1ull << lane) - 1ull));
                        s_buf[base + pfx] = mono_u(x);
                    }
                }
            }
        }
        __syncthreads();
        cnt = s_cnt;
    }

    // ---- Round V: linear value histogram -> narrow to one value bin ----
    int kp = k;
    hist[tid] = 0;
    __syncthreads();
    for (int i = tid; i < cnt; i += BLK) {
        float x = unmono_f(s_buf[i]);
        atomicAdd(&hist[vbin_of(x)], 1u);
    }
    __syncthreads();
    find_bin(hist, kp, tid, s_sel);
    __syncthreads();
    const int bv = s_sel[0];
    kp -= s_sel[1];

    // ---- 4 exact 8-bit radix rounds over crossing-bin candidates ----
    uint32_t prefix = 0;
    for (int r = 0; r < 4; ++r) {
        const int shift = 24 - 8 * r;
        hist[tid] = 0;
        __syncthreads();
        for (int i = tid; i < cnt; i += BLK) {
            uint32_t u = s_buf[i];
            float x = unmono_f(u);
            bool match = (vbin_of(x) == bv);
            if (r > 0) match = match && ((u >> (shift + 8)) == (prefix >> (shift + 8)));
            if (match) atomicAdd(&hist[(u >> shift) & 255u], 1u);
        }
        __syncthreads();
        find_bin(hist, kp, tid, s_sel);
        __syncthreads();
        prefix |= ((uint32_t)s_sel[0]) << shift;
        kp -= s_sel[1];
    }
    // prefix == exact uint of k-th largest value; kp == #elements equal to it to include

    // ---- Final: sum softplus over selected ----
    const uint32_t tu = prefix;
    float gsum = 0.0f;
    for (int i = tid; i < cnt; i += BLK) {
        uint32_t u = s_buf[i];
        if (u > tu) gsum += sp_f(unmono_f(u));
    }
    float tot = gsum + pos_loss;
    #pragma unroll
    for (int off = 32; off; off >>= 1) tot += __shfl_down(tot, off);
    if (lane == 0) f_scr[tid >> 6] = tot;
    __syncthreads();
    if (tid == 0) {
        float rowsum = f_scr[0] + f_scr[1] + f_scr[2] + f_scr[3]
                     + (float)kp * sp_f(unmono_f(tu));
        atomicAdd(num_acc, (double)rowsum);
        atomicAdd(den_acc, (float)pos_total);   // exact: integer-valued, < 2^24
    }
}

__global__ void hardneg_finalize(const double* __restrict__ num_acc,
                                 const float* __restrict__ den_acc,
                                 float* __restrict__ out)
{
    if (threadIdx.x == 0 && blockIdx.x == 0) {
        float d = *den_acc;
        out[0] = (d > 0.0f) ? (float)(*num_acc / (double)d) : 0.0f;
    }
}

extern "C" void kernel_launch(void* const* d_in, const int* in_sizes, int n_in,
                              void* d_out, int out_size, void* d_ws, size_t ws_size,
                              hipStream_t stream) {
    const float* pred = (const float*)d_in[0];
    const float* target = (const float*)d_in[1];
    float* out = (float*)d_out;

    double* num_acc = (double*)d_ws;
    float* den_acc = (float*)((char*)d_ws + 8);

    // d_ws is re-poisoned to 0xAA before every timed launch -> zero accumulators here
    hipMemsetAsync(d_ws, 0, 16, stream);

    const int nrows = in_sizes[0] / C_DIM;   // 8192
    hardneg_kernel<<<nrows, BLK, 0, stream>>>(pred, target, num_acc, den_acc);
    hardneg_finalize<<<1, 64, 0, stream>>>(num_acc, den_acc, out);
}

// Round 3
// 462.403 us; speedup vs baseline: 1.0413x; 1.0413x over previous
//
#include <hip/hip_runtime.h>
#include <stdint.h>

// HardNegLoss: N=8192 rows, C=5000 classes.
// loss = [ sum_pos (softplus(x)-x) + sum_{top-k negatives by pred} softplus(x) ] / sum(target)
// k = min(3*pos, C-pos). Top-k of raw pred among negatives == reference's
// argsort-of-(softmax - target) selection; ties handled by count (value-exact).

#define C_DIM 5000
#define C4_DIM 1250
#define BLK 256
#define CAP 5120          // holds all 5000 elements -> fallback always fits
#define CUT 1.25f         // stage only negatives > CUT (~520/row); fallback if k > staged

__device__ __forceinline__ float sp_f(float x) {
    // softplus via HW v_exp_f32/v_log_f32 (rel err ~1e-6, loss tolerance 0.158)
    return fmaxf(x, 0.0f) + __logf(1.0f + __expf(-fabsf(x)));
}
__device__ __forceinline__ uint32_t mono_u(float x) {
    uint32_t b = __float_as_uint(x);
    return b ^ ((b & 0x80000000u) ? 0xFFFFFFFFu : 0x80000000u);
}
__device__ __forceinline__ float unmono_f(uint32_t u) {
    uint32_t b = (u & 0x80000000u) ? (u ^ 0x80000000u) : ~u;
    return __uint_as_float(b);
}
__device__ __forceinline__ int vbin_of(float x) {
    // linear bins width 1/128 over [CUT, CUT+2): expected crossing-bin count ~3
    int v = (int)((x - CUT) * 128.0f);
    return v > 255 ? 255 : (v < 0 ? 0 : v);
}

// crossing bin for kp-th largest from 256-bin hist (bins high=large), wave 0.
// s_sel[0]=bin, s_sel[1]=count strictly above it.
__device__ __forceinline__ void find_bin(const unsigned int* hist, int kp, int tid, int* s_sel) {
    if (tid < 64) {
        int c0 = (int)hist[4 * tid + 0];
        int c1 = (int)hist[4 * tid + 1];
        int c2 = (int)hist[4 * tid + 2];
        int c3 = (int)hist[4 * tid + 3];
        int lsum = c0 + c1 + c2 + c3;
        int s = lsum;
        #pragma unroll
        for (int off = 1; off < 64; off <<= 1) {
            int o = __shfl_down(s, off);
            if (tid + off < 64) s += o;
        }
        int above = s - lsum;
        if (above < kp && kp <= s) {
            int b, ab;
            if (kp <= above + c3)                { b = 4 * tid + 3; ab = above; }
            else if (kp <= above + c3 + c2)      { b = 4 * tid + 2; ab = above + c3; }
            else if (kp <= above + c3 + c2 + c1) { b = 4 * tid + 1; ab = above + c3 + c2; }
            else                                 { b = 4 * tid;     ab = above + c3 + c2 + c1; }
            s_sel[0] = b;
            s_sel[1] = ab;
        }
    }
}

__global__ __launch_bounds__(BLK) void hardneg_kernel(
    const float* __restrict__ pred, const float* __restrict__ target,
    double* __restrict__ num_acc, float* __restrict__ den_acc)
{
    __shared__ uint32_t s_buf[CAP];      // cands (mono-u) from front, positives (raw f32) from back
    __shared__ unsigned int hist[256];
    __shared__ unsigned int w_scr[4];
    __shared__ float f_scr[4];
    __shared__ int s_sel[2];
    __shared__ int s_misc[4];            // [0]=tiny cnt, [1]=tu, [2]=n_at, [3]=append cnt
    __shared__ uint32_t s_tiny[64];

    const int tid = threadIdx.x;
    const int lane = tid & 63;
    const int wv = tid >> 6;
    const int row = blockIdx.x;
    const float4* pr4 = (const float4*)(pred + (size_t)row * C_DIM);
    const float4* tg4 = (const float4*)(target + (size_t)row * C_DIM);

    hist[tid] = 0;
    if (tid < 4) s_misc[tid] = 0;

    // ---- loop1: 5 chunks into registers, build candidate/positive bitmasks ----
    float px[20];
    uint32_t cmask = 0, pmask = 0;
    #pragma unroll
    for (int c = 0; c < 5; ++c) {
        int i = tid + c * BLK;
        float4 p = {0.f, 0.f, 0.f, 0.f}, t = {0.f, 0.f, 0.f, 0.f};
        if (c < 4 || i < C4_DIM) { p = pr4[i]; t = tg4[i]; }   // c<4 folds at compile time
        px[4*c+0] = p.x; px[4*c+1] = p.y; px[4*c+2] = p.z; px[4*c+3] = p.w;
        if (t.x != 0.f) pmask |= 1u << (4*c+0); else if (p.x > CUT) cmask |= 1u << (4*c+0);
        if (t.y != 0.f) pmask |= 1u << (4*c+1); else if (p.y > CUT) cmask |= 1u << (4*c+1);
        if (t.z != 0.f) pmask |= 1u << (4*c+2); else if (p.z > CUT) cmask |= 1u << (4*c+2);
        if (t.w != 0.f) pmask |= 1u << (4*c+3); else if (p.w > CUT) cmask |= 1u << (4*c+3);
    }

    // ---- block prefix-sum of packed (cand | pos<<16) counts ----
    unsigned int pk = (unsigned int)__popc(cmask) | ((unsigned int)__popc(pmask) << 16);
    unsigned int s = pk;
    #pragma unroll
    for (int off = 1; off < 64; off <<= 1) {
        unsigned int o = (unsigned int)__shfl_up((int)s, off);
        if (lane >= off) s += o;
    }
    if (lane == 63) w_scr[wv] = s;
    __syncthreads();
    unsigned int wb = 0;
    for (int w = 0; w < wv; ++w) wb += w_scr[w];
    const unsigned int tot = w_scr[0] + w_scr[1] + w_scr[2] + w_scr[3];
    const int cand_total = (int)(tot & 0xFFFFu);
    const int pos_total  = (int)(tot >> 16);
    const unsigned int excl = wb + s - pk;
    int cb = (int)(excl & 0xFFFFu);
    int pb = (int)(excl >> 16);

    const int k = min(3 * pos_total, C_DIM - pos_total);
    if (k == 0) return;   // uniform: no mask, no denominator contribution

    // ---- loop2: replay masks, write staged values (static indices -> registers) ----
    #pragma unroll
    for (int e = 0; e < 20; ++e) {
        if (cmask & (1u << e)) {
            s_buf[cb++] = __float_as_uint(px[e]) ^ 0x80000000u;  // mono_u for x>0
        } else if (pmask & (1u << e)) {
            s_buf[CAP - 1 - (pb++)] = __float_as_uint(px[e]);
        }
    }
    __syncthreads();

    int cnt = cand_total;

    // ---- deferred positives (~50/row): one short scan ----
    float acc = 0.0f;
    for (int i = tid; i < pos_total; i += BLK) {
        float x = __uint_as_float(s_buf[CAP - 1 - i]);
        acc += sp_f(x) - x;
    }

    // ---- fallback (practically never: k<=~250 << cnt~520): append x<=CUT negatives ----
    if (k > cnt) {
        if (tid == 0) s_misc[3] = cnt;
        __syncthreads();
        for (int i = tid; i < C4_DIM; i += BLK) {
            float4 p = pr4[i];
            float4 t = tg4[i];
            float pxl[4] = {p.x, p.y, p.z, p.w};
            float txl[4] = {t.x, t.y, t.z, t.w};
            #pragma unroll
            for (int j = 0; j < 4; ++j) {
                bool cand = (txl[j] == 0.0f) && !(pxl[j] > CUT);
                unsigned long long m = __ballot(cand);
                if (m) {
                    int c = __popcll(m);
                    int leader = __ffsll((unsigned long long)m) - 1;
                    int base = 0;
                    if (lane == leader) base = atomicAdd(&s_misc[3], c);
                    base = __shfl(base, leader);
                    if (cand) {
                        int pfx = __popcll(m & ((1ull << lane) - 1ull));
                        s_buf[base + pfx] = mono_u(pxl[j]);
                    }
                }
            }
        }
        __syncthreads();
        cnt = s_misc[3];
    }

    // ---- histogram staged candidates (2 iterations) ----
    for (int i = tid; i < cnt; i += BLK) {
        atomicAdd(&hist[vbin_of(unmono_f(s_buf[i]))], 1u);
    }
    __syncthreads();
    find_bin(hist, k, tid, s_sel);
    __syncthreads();
    const int bv = s_sel[0];
    int kp = k - s_sel[1];

    // ---- gather crossing-bin elements (expected ~3) ----
    for (int i = tid; i < cnt; i += BLK) {
        uint32_t u = s_buf[i];
        if (vbin_of(unmono_f(u)) == bv) {
            int idx = atomicAdd(&s_misc[0], 1);
            if (idx < 64) s_tiny[idx] = u;
        }
    }
    __syncthreads();
    const int tcnt = s_misc[0];

    uint32_t tu;
    int n_at;
    if (tcnt <= 64) {
        // exact rank among <=64 values on wave 0 via shfl broadcast
        if (tid < 64) {
            uint32_t ul = (lane < tcnt) ? s_tiny[lane] : 0u;
            int sg = 0, eq = 0;
            for (int j = 0; j < tcnt; ++j) {
                uint32_t uj = (uint32_t)__shfl((int)ul, j);
                sg += (uj > ul);
                eq += (uj == ul);
            }
            if (lane < tcnt && sg < kp && kp <= sg + eq) {
                s_misc[1] = (int)ul;       // all matching lanes (tie group) write same values
                s_misc[2] = kp - sg;
            }
        }
        __syncthreads();
        tu = (uint32_t)s_misc[1];
        n_at = s_misc[2];
    } else {
        // robust fallback: 4 exact 8-bit radix rounds within bin bv
        uint32_t prefix = 0;
        for (int r = 0; r < 4; ++r) {
            const int shift = 24 - 8 * r;
            hist[tid] = 0;
            __syncthreads();
            for (int i = tid; i < cnt; i += BLK) {
                uint32_t u = s_buf[i];
                bool match = (vbin_of(unmono_f(u)) == bv);
                if (r > 0) match = match && ((u >> (shift + 8)) == (prefix >> (shift + 8)));
                if (match) atomicAdd(&hist[(u >> shift) & 255u], 1u);
            }
            __syncthreads();
            find_bin(hist, kp, tid, s_sel);
            __syncthreads();
            prefix |= ((uint32_t)s_sel[0]) << shift;
            kp -= s_sel[1];
        }
        tu = prefix;
        n_at = kp;
    }

    // ---- final: sum softplus over selected (u > tu), + n_at ties ----
    for (int i = tid; i < cnt; i += BLK) {
        uint32_t u = s_buf[i];
        if (u > tu) acc += sp_f(unmono_f(u));
    }
    #pragma unroll
    for (int off = 32; off; off >>= 1) acc += __shfl_down(acc, off);
    if (lane == 0) f_scr[wv] = acc;
    __syncthreads();
    if (tid == 0) {
        float rowsum = f_scr[0] + f_scr[1] + f_scr[2] + f_scr[3]
                     + (float)n_at * sp_f(unmono_f(tu));
        atomicAdd(num_acc, (double)rowsum);
        atomicAdd(den_acc, (float)pos_total);   // exact: integer-valued, < 2^24
    }
}

__global__ void hardneg_finalize(const double* __restrict__ num_acc,
                                 const float* __restrict__ den_acc,
                                 float* __restrict__ out)
{
    if (threadIdx.x == 0 && blockIdx.x == 0) {
        float d = *den_acc;
        out[0] = (d > 0.0f) ? (float)(*num_acc / (double)d) : 0.0f;
    }
}

extern "C" void kernel_launch(void* const* d_in, const int* in_sizes, int n_in,
                              void* d_out, int out_size, void* d_ws, size_t ws_size,
                              hipStream_t stream) {
    const float* pred = (const float*)d_in[0];
    const float* target = (const float*)d_in[1];
    float* out = (float*)d_out;

    double* num_acc = (double*)d_ws;
    float* den_acc = (float*)((char*)d_ws + 8);

    // d_ws is re-poisoned to 0xAA before every timed launch -> zero accumulators here
    hipMemsetAsync(d_ws, 0, 16, stream);

    const int nrows = in_sizes[0] / C_DIM;   // 8192
    hardneg_kernel<<<nrows, BLK, 0, stream>>>(pred, target, num_acc, den_acc);
    hardneg_finalize<<<1, 64, 0, stream>>>(num_acc, den_acc, out);
}

// Round 4
// 337.626 us; speedup vs baseline: 1.4261x; 1.3696x over previous
//
#include <hip/hip_runtime.h>
#include <stdint.h>

// HardNegLoss: N=8192 rows, C=5000 classes.
// loss = [ sum_pos (softplus(x)-x) + sum_{top-k negatives by pred} softplus(x) ] / sum(target)
// k = min(3*pos, C-pos). Top-k of raw pred among negatives == reference's
// argsort-of-(softmax - target) selection; ties handled by count (value-exact).

#define C_DIM 5000
#define C4_DIM 1250
#define BLK 256
#define SCAP 1024         // staged candidates (~520 expected, 23 sigma headroom)
#define CUT 1.25f         // stage negatives > CUT; exact global fallback otherwise
#define NSLOT 64

__device__ __forceinline__ float sp_f(float x) {
    // softplus via HW v_exp_f32/v_log_f32 (rel err ~1e-6 vs 0.158 tolerance)
    return fmaxf(x, 0.0f) + __logf(1.0f + __expf(-fabsf(x)));
}
__device__ __forceinline__ uint32_t mono_u(float x) {
    uint32_t b = __float_as_uint(x);
    return b ^ ((b & 0x80000000u) ? 0xFFFFFFFFu : 0x80000000u);
}
__device__ __forceinline__ float unmono_f(uint32_t u) {
    uint32_t b = (u & 0x80000000u) ? (u ^ 0x80000000u) : ~u;
    return __uint_as_float(b);
}
__device__ __forceinline__ int vbin_of(float x) {
    // linear bins width 1/128 over [CUT, CUT+2): ~2-3 staged values per bin
    int v = (int)((x - CUT) * 128.0f);
    return v > 255 ? 255 : (v < 0 ? 0 : v);
}

// crossing bin for kp-th largest from 256-bin hist (bins high=large), wave 0.
// s_sel[0]=bin, s_sel[1]=count strictly above it.
__device__ __forceinline__ void find_bin(const unsigned int* hist, int kp, int tid, int* s_sel) {
    if (tid < 64) {
        int c0 = (int)hist[4 * tid + 0];
        int c1 = (int)hist[4 * tid + 1];
        int c2 = (int)hist[4 * tid + 2];
        int c3 = (int)hist[4 * tid + 3];
        int lsum = c0 + c1 + c2 + c3;
        int s = lsum;
        #pragma unroll
        for (int off = 1; off < 64; off <<= 1) {
            int o = __shfl_down(s, off);
            if (tid + off < 64) s += o;
        }
        int above = s - lsum;
        if (above < kp && kp <= s) {
            int b, ab;
            if (kp <= above + c3)                { b = 4 * tid + 3; ab = above; }
            else if (kp <= above + c3 + c2)      { b = 4 * tid + 2; ab = above + c3; }
            else if (kp <= above + c3 + c2 + c1) { b = 4 * tid + 1; ab = above + c3 + c2; }
            else                                 { b = 4 * tid;     ab = above + c3 + c2 + c1; }
            s_sel[0] = b;
            s_sel[1] = ab;
        }
    }
}

__global__ __launch_bounds__(BLK, 8) void hardneg_kernel(
    const float* __restrict__ pred, const float* __restrict__ target,
    char* __restrict__ ws)
{
    __shared__ uint32_t s_buf[SCAP];
    __shared__ unsigned int hist[256];
    __shared__ int i_scr[4];
    __shared__ float f_scr[4];
    __shared__ int s_sel[2];
    __shared__ int s_misc[4];       // [0]=tiny cnt, [1]=tu, [2]=n_at
    __shared__ int s_cnt;
    __shared__ uint32_t s_tiny[64];

    const int tid = threadIdx.x;
    const int lane = tid & 63;
    const int wv = tid >> 6;
    const int row = blockIdx.x;
    const float4* pr4 = (const float4*)(pred + (size_t)row * C_DIM);
    const float4* tg4 = (const float4*)(target + (size_t)row * C_DIM);

    hist[tid] = 0;
    if (tid < 4) { i_scr[tid] = 0; s_misc[tid] = 0; }
    if (tid == 0) s_cnt = 0;
    __syncthreads();   // hist fully zeroed before any inline atomic

    float acc = 0.0f;
    int pos_cnt = 0;

    // ---- single streaming pass: classify, inline positives, inline histogram,
    //      per-chunk prefix-sum compaction into LDS (no live arrays across barriers)
    for (int c = 0; c < 5; ++c) {
        int i = tid + c * BLK;
        float4 p = {0.f, 0.f, 0.f, 0.f}, t = {0.f, 0.f, 0.f, 0.f};
        if (i < C4_DIM) { p = pr4[i]; t = tg4[i]; }
        float xs[4] = {p.x, p.y, p.z, p.w};
        float ts[4] = {t.x, t.y, t.z, t.w};
        float cv0 = 0.f, cv1 = 0.f, cv2 = 0.f, cv3 = 0.f;
        int nc = 0;
        #pragma unroll
        for (int j = 0; j < 4; ++j) {
            float x = xs[j];
            if (ts[j] != 0.0f) {
                pos_cnt++;
                acc += sp_f(x) - x;
            } else if (x > CUT) {
                atomicAdd(&hist[vbin_of(x)], 1u);
                if (nc == 0) cv0 = x; else if (nc == 1) cv1 = x;
                else if (nc == 2) cv2 = x; else cv3 = x;
                ++nc;
            }
        }
        // wave inclusive prefix of nc (6 shfl + 6 add)
        unsigned pfx = (unsigned)nc;
        #pragma unroll
        for (int off = 1; off < 64; off <<= 1) {
            unsigned o = (unsigned)__shfl_up((int)pfx, off);
            if (lane >= off) pfx += o;
        }
        int base = 0;
        if (lane == 63) base = atomicAdd(&s_cnt, (int)pfx);
        base = __shfl(base, 63);
        int w = base + (int)pfx - nc;   // exclusive offset
        // cv* > CUT > 0 -> mono_u == bits ^ 0x80000000
        if (nc > 0 && w + 0 < SCAP) s_buf[w + 0] = __float_as_uint(cv0) ^ 0x80000000u;
        if (nc > 1 && w + 1 < SCAP) s_buf[w + 1] = __float_as_uint(cv1) ^ 0x80000000u;
        if (nc > 2 && w + 2 < SCAP) s_buf[w + 2] = __float_as_uint(cv2) ^ 0x80000000u;
        if (nc > 3 && w + 3 < SCAP) s_buf[w + 3] = __float_as_uint(cv3) ^ 0x80000000u;
    }

    // ---- block reduce positives count ----
    int v = pos_cnt;
    #pragma unroll
    for (int off = 32; off; off >>= 1) v += __shfl_down(v, off);
    if (lane == 0) i_scr[wv] = v;
    __syncthreads();
    const int pos_total = i_scr[0] + i_scr[1] + i_scr[2] + i_scr[3];
    const int k = min(3 * pos_total, C_DIM - pos_total);
    const int cnt = s_cnt;
    if (k == 0) return;   // uniform: no mask, no denominator contribution

    uint32_t tu;
    int n_at;
    const bool fb = (k > cnt) || (cnt > SCAP);   // block-uniform

    if (!fb) {
        // ---- narrow to crossing value-bin (hist already built) ----
        find_bin(hist, k, tid, s_sel);
        __syncthreads();
        const int bv = s_sel[0];
        int kp = k - s_sel[1];

        // ---- gather crossing-bin elements (expected ~3) ----
        for (int i = tid; i < cnt; i += BLK) {
            uint32_t u = s_buf[i];
            if (vbin_of(unmono_f(u)) == bv) {
                int idx = atomicAdd(&s_misc[0], 1);
                if (idx < 64) s_tiny[idx] = u;
            }
        }
        __syncthreads();
        const int tcnt = s_misc[0];

        if (tcnt <= 64) {
            // exact rank among <=64 values on wave 0
            if (tid < 64) {
                uint32_t ul = (lane < tcnt) ? s_tiny[lane] : 0u;
                int sg = 0, eq = 0;
                for (int j = 0; j < tcnt; ++j) {
                    uint32_t uj = (uint32_t)__shfl((int)ul, j);
                    sg += (uj > ul);
                    eq += (uj == ul);
                }
                if (lane < tcnt && sg < kp && kp <= sg + eq) {
                    s_misc[1] = (int)ul;   // tie-group lanes write identical values
                    s_misc[2] = kp - sg;
                }
            }
            __syncthreads();
            tu = (uint32_t)s_misc[1];
            n_at = s_misc[2];
        } else {
            // robust fallback: exact 8-bit radix within bin bv over staged values
            uint32_t prefix = 0;
            for (int r = 0; r < 4; ++r) {
                const int shift = 24 - 8 * r;
                __syncthreads();
                hist[tid] = 0;
                __syncthreads();
                for (int i = tid; i < cnt; i += BLK) {
                    uint32_t u = s_buf[i];
                    bool match = (vbin_of(unmono_f(u)) == bv);
                    if (r > 0) match = match && ((u >> (shift + 8)) == (prefix >> (shift + 8)));
                    if (match) atomicAdd(&hist[(u >> shift) & 255u], 1u);
                }
                __syncthreads();
                find_bin(hist, kp, tid, s_sel);
                __syncthreads();
                prefix |= ((uint32_t)s_sel[0]) << shift;
                kp -= s_sel[1];
            }
            tu = prefix;
            n_at = kp;
        }

        // ---- final: sum softplus over staged selected (u > tu) ----
        for (int i = tid; i < cnt; i += BLK) {
            uint32_t u = s_buf[i];
            if (u > tu) acc += sp_f(unmono_f(u));
        }
    } else {
        // ---- cold exact fallback (k > staged or overflow): radix over all
        //      negatives, re-reading global (L2-resident). Never taken for this data.
        uint32_t prefix = 0;
        int kq = k;
        for (int r = 0; r < 4; ++r) {
            const int shift = 24 - 8 * r;
            __syncthreads();
            hist[tid] = 0;
            __syncthreads();
            for (int i = tid; i < C4_DIM; i += BLK) {
                float4 p = pr4[i];
                float4 t = tg4[i];
                float xs[4] = {p.x, p.y, p.z, p.w};
                float ts[4] = {t.x, t.y, t.z, t.w};
                #pragma unroll
                for (int j = 0; j < 4; ++j) {
                    if (ts[j] == 0.0f) {
                        uint32_t u = mono_u(xs[j]);
                        bool m = (r == 0) || ((u >> (shift + 8)) == (prefix >> (shift + 8)));
                        if (m) atomicAdd(&hist[(u >> shift) & 255u], 1u);
                    }
                }
            }
            __syncthreads();
            find_bin(hist, kq, tid, s_sel);
            __syncthreads();
            prefix |= ((uint32_t)s_sel[0]) << shift;
            kq -= s_sel[1];
        }
        tu = prefix;
        n_at = kq;
        for (int i = tid; i < C4_DIM; i += BLK) {
            float4 p = pr4[i];
            float4 t = tg4[i];
            float xs[4] = {p.x, p.y, p.z, p.w};
            float ts[4] = {t.x, t.y, t.z, t.w};
            #pragma unroll
            for (int j = 0; j < 4; ++j) {
                if (ts[j] == 0.0f) {
                    uint32_t u = mono_u(xs[j]);
                    if (u > tu) acc += sp_f(xs[j]);
                }
            }
        }
    }

    // ---- block reduce + slot-hashed global accumulate ----
    #pragma unroll
    for (int off = 32; off; off >>= 1) acc += __shfl_down(acc, off);
    if (lane == 0) f_scr[wv] = acc;
    __syncthreads();
    if (tid == 0) {
        float rowsum = f_scr[0] + f_scr[1] + f_scr[2] + f_scr[3]
                     + (float)n_at * sp_f(unmono_f(tu));
        char* slot = ws + (size_t)(row & (NSLOT - 1)) * 16;
        atomicAdd((double*)slot, (double)rowsum);
        atomicAdd((float*)(slot + 8), (float)pos_total);   // exact: int-valued < 2^24
    }
}

__global__ void hardneg_finalize(const char* __restrict__ ws, float* __restrict__ out)
{
    const int l = threadIdx.x;   // 64 threads
    double n = *(const double*)(ws + (size_t)l * 16);
    float d = *(const float*)(ws + (size_t)l * 16 + 8);
    #pragma unroll
    for (int off = 32; off; off >>= 1) {
        n += __shfl_down(n, off);
        d += __shfl_down(d, off);
    }
    if (l == 0) out[0] = (d > 0.0f) ? (float)(n / (double)d) : 0.0f;
}

extern "C" void kernel_launch(void* const* d_in, const int* in_sizes, int n_in,
                              void* d_out, int out_size, void* d_ws, size_t ws_size,
                              hipStream_t stream) {
    const float* pred = (const float*)d_in[0];
    const float* target = (const float*)d_in[1];
    float* out = (float*)d_out;
    char* ws = (char*)d_ws;

    // d_ws re-poisoned to 0xAA before every timed launch -> zero the 64 slots
    hipMemsetAsync(ws, 0, NSLOT * 16, stream);

    const int nrows = in_sizes[0] / C_DIM;   // 8192
    hardneg_kernel<<<nrows, BLK, 0, stream>>>(pred, target, ws);
    hardneg_finalize<<<1, 64, 0, stream>>>(ws, out);
}

// Round 5
// 337.244 us; speedup vs baseline: 1.4277x; 1.0011x over previous
//
#include <hip/hip_runtime.h>
#include <stdint.h>

// HardNegLoss: N=8192 rows, C=5000 classes.
// loss = [ sum_pos (softplus(x)-x) + sum_{top-k negatives by pred} softplus(x) ] / sum(target)
// k = min(3*pos, C-pos). Top-k of raw pred among negatives == reference's
// argsort-of-(softmax - target) selection; ties handled by count (value-exact).

#define C_DIM 5000
#define C4_DIM 1250
#define BLK 256
#define SCAP 1024         // staged candidates (~520 expected; 23 sigma headroom)
#define PCAP 512          // staged positives (~50 expected)
#define CUT 1.25f         // stage negatives > CUT; exact global fallback otherwise
#define NSLOT 64

__device__ __forceinline__ float sp_f(float x) {
    // softplus via HW v_exp_f32/v_log_f32 (rel err ~1e-6 vs 0.158 tolerance)
    return fmaxf(x, 0.0f) + __logf(1.0f + __expf(-fabsf(x)));
}
__device__ __forceinline__ uint32_t mono_u(float x) {
    uint32_t b = __float_as_uint(x);
    return b ^ ((b & 0x80000000u) ? 0xFFFFFFFFu : 0x80000000u);
}
__device__ __forceinline__ float unmono_f(uint32_t u) {
    uint32_t b = (u & 0x80000000u) ? (u ^ 0x80000000u) : ~u;
    return __uint_as_float(b);
}
__device__ __forceinline__ int vbin_of(float x) {
    // linear bins width 1/128 over [CUT, CUT+2): ~2-3 staged values per bin
    int v = (int)((x - CUT) * 128.0f);
    return v > 255 ? 255 : (v < 0 ? 0 : v);
}

// crossing bin for kp-th largest from 256-bin hist (bins high=large), wave 0.
// s_sel[0]=bin, s_sel[1]=count strictly above it.
__device__ __forceinline__ void find_bin(const unsigned int* hist, int kp, int tid, int* s_sel) {
    if (tid < 64) {
        int c0 = (int)hist[4 * tid + 0];
        int c1 = (int)hist[4 * tid + 1];
        int c2 = (int)hist[4 * tid + 2];
        int c3 = (int)hist[4 * tid + 3];
        int lsum = c0 + c1 + c2 + c3;
        int s = lsum;
        #pragma unroll
        for (int off = 1; off < 64; off <<= 1) {
            int o = __shfl_down(s, off);
            if (tid + off < 64) s += o;
        }
        int above = s - lsum;
        if (above < kp && kp <= s) {
            int b, ab;
            if (kp <= above + c3)                { b = 4 * tid + 3; ab = above; }
            else if (kp <= above + c3 + c2)      { b = 4 * tid + 2; ab = above + c3; }
            else if (kp <= above + c3 + c2 + c1) { b = 4 * tid + 1; ab = above + c3 + c2; }
            else                                 { b = 4 * tid;     ab = above + c3 + c2 + c1; }
            s_sel[0] = b;
            s_sel[1] = ab;
        }
    }
}

__global__ __launch_bounds__(BLK, 4) void hardneg_kernel(
    const float* __restrict__ pred, const float* __restrict__ target,
    char* __restrict__ ws)
{
    __shared__ uint32_t s_buf[SCAP];     // candidate mono-u values
    __shared__ uint32_t s_pbuf[PCAP];    // positive raw f32 bits
    __shared__ unsigned int hist[256];
    __shared__ float f_scr[4];
    __shared__ int s_sel[2];
    __shared__ int s_misc[4];            // [0]=tiny cnt, [1]=tu, [2]=n_at
    __shared__ int s_cnt;                // candidate counter
    __shared__ int s_pcnt;               // positive counter
    __shared__ uint32_t s_tiny[64];

    const int tid = threadIdx.x;
    const int lane = tid & 63;
    const int wv = tid >> 6;
    const int row = blockIdx.x;
    const float4* pr4 = (const float4*)(pred + (size_t)row * C_DIM);
    const float4* tg4 = (const float4*)(target + (size_t)row * C_DIM);

    hist[tid] = 0;
    if (tid < 4) s_misc[tid] = 0;
    if (tid == 0) { s_cnt = 0; s_pcnt = 0; }
    __syncthreads();   // counters/hist zeroed before any atomic

    // ---- hot streaming pass: no barriers, no cross-lane ops, per-element
    //      LDS-atomic slot allocation. Full unroll -> all 10 loads hoisted.
    #pragma unroll
    for (int c = 0; c < 5; ++c) {
        int i = tid + c * BLK;
        if (c < 4 || i < C4_DIM) {
            float4 p = pr4[i];
            float4 t = tg4[i];
            float xs[4] = {p.x, p.y, p.z, p.w};
            float ts[4] = {t.x, t.y, t.z, t.w};
            #pragma unroll
            for (int j = 0; j < 4; ++j) {
                float x = xs[j];
                if (ts[j] != 0.0f) {
                    int ip = atomicAdd(&s_pcnt, 1);
                    if (ip < PCAP) s_pbuf[ip] = __float_as_uint(x);
                } else if (x > CUT) {
                    int ic = atomicAdd(&s_cnt, 1);
                    // x > CUT > 0 -> mono_u == bits ^ 0x80000000
                    if (ic < SCAP) s_buf[ic] = __float_as_uint(x) ^ 0x80000000u;
                }
            }
        }
    }
    __syncthreads();

    const int pos_total = s_pcnt;
    const int cnt = s_cnt;
    const int k = min(3 * pos_total, C_DIM - pos_total);
    if (k == 0) return;   // uniform: no mask, no denominator contribution

    // ---- positives (~50): one short masked pass over staged buffer ----
    float acc = 0.0f;
    if (pos_total <= PCAP) {
        for (int i = tid; i < pos_total; i += BLK) {
            float x = __uint_as_float(s_pbuf[i]);
            acc += sp_f(x) - x;
        }
    } else {
        // cold exact fallback: re-read global (never for this data)
        for (int i = tid; i < C4_DIM; i += BLK) {
            float4 p = pr4[i];
            float4 t = tg4[i];
            float xs[4] = {p.x, p.y, p.z, p.w};
            float ts[4] = {t.x, t.y, t.z, t.w};
            #pragma unroll
            for (int j = 0; j < 4; ++j)
                if (ts[j] != 0.0f) acc += sp_f(xs[j]) - xs[j];
        }
    }

    uint32_t tu;
    int n_at;
    const bool fb = (k > cnt) || (cnt > SCAP);   // block-uniform

    if (!fb) {
        // ---- hist over staged candidates (~2 iterations) ----
        for (int i = tid; i < cnt; i += BLK)
            atomicAdd(&hist[vbin_of(unmono_f(s_buf[i]))], 1u);
        __syncthreads();
        find_bin(hist, k, tid, s_sel);
        __syncthreads();
        const int bv = s_sel[0];
        int kp = k - s_sel[1];

        // ---- gather crossing-bin elements (expected ~3) ----
        for (int i = tid; i < cnt; i += BLK) {
            uint32_t u = s_buf[i];
            if (vbin_of(unmono_f(u)) == bv) {
                int idx = atomicAdd(&s_misc[0], 1);
                if (idx < 64) s_tiny[idx] = u;
            }
        }
        __syncthreads();
        const int tcnt = s_misc[0];

        if (tcnt <= 64) {
            // exact rank among <=64 values on wave 0
            if (tid < 64) {
                uint32_t ul = (lane < tcnt) ? s_tiny[lane] : 0u;
                int sg = 0, eq = 0;
                for (int j = 0; j < tcnt; ++j) {
                    uint32_t uj = (uint32_t)__shfl((int)ul, j);
                    sg += (uj > ul);
                    eq += (uj == ul);
                }
                if (lane < tcnt && sg < kp && kp <= sg + eq) {
                    s_misc[1] = (int)ul;   // tie-group lanes write identical values
                    s_misc[2] = kp - sg;
                }
            }
            __syncthreads();
            tu = (uint32_t)s_misc[1];
            n_at = s_misc[2];
        } else {
            // robust: exact 8-bit radix within bin bv over staged values
            uint32_t prefix = 0;
            for (int r = 0; r < 4; ++r) {
                const int shift = 24 - 8 * r;
                __syncthreads();
                hist[tid] = 0;
                __syncthreads();
                for (int i = tid; i < cnt; i += BLK) {
                    uint32_t u = s_buf[i];
                    bool match = (vbin_of(unmono_f(u)) == bv);
                    if (r > 0) match = match && ((u >> (shift + 8)) == (prefix >> (shift + 8)));
                    if (match) atomicAdd(&hist[(u >> shift) & 255u], 1u);
                }
                __syncthreads();
                find_bin(hist, kp, tid, s_sel);
                __syncthreads();
                prefix |= ((uint32_t)s_sel[0]) << shift;
                kp -= s_sel[1];
            }
            tu = prefix;
            n_at = kp;
        }

        // ---- final: sum softplus over staged selected (u > tu) ----
        for (int i = tid; i < cnt; i += BLK) {
            uint32_t u = s_buf[i];
            if (u > tu) acc += sp_f(unmono_f(u));
        }
    } else {
        // ---- cold exact fallback (k > staged or overflow): radix over all
        //      negatives, re-reading global (L2/L3-resident). Never for this data.
        uint32_t prefix = 0;
        int kq = k;
        for (int r = 0; r < 4; ++r) {
            const int shift = 24 - 8 * r;
            __syncthreads();
            hist[tid] = 0;
            __syncthreads();
            for (int i = tid; i < C4_DIM; i += BLK) {
                float4 p = pr4[i];
                float4 t = tg4[i];
                float xs[4] = {p.x, p.y, p.z, p.w};
                float ts[4] = {t.x, t.y, t.z, t.w};
                #pragma unroll
                for (int j = 0; j < 4; ++j) {
                    if (ts[j] == 0.0f) {
                        uint32_t u = mono_u(xs[j]);
                        bool m = (r == 0) || ((u >> (shift + 8)) == (prefix >> (shift + 8)));
                        if (m) atomicAdd(&hist[(u >> shift) & 255u], 1u);
                    }
                }
            }
            __syncthreads();
            find_bin(hist, kq, tid, s_sel);
            __syncthreads();
            prefix |= ((uint32_t)s_sel[0]) << shift;
            kq -= s_sel[1];
        }
        tu = prefix;
        n_at = kq;
        for (int i = tid; i < C4_DIM; i += BLK) {
            float4 p = pr4[i];
            float4 t = tg4[i];
            float xs[4] = {p.x, p.y, p.z, p.w};
            float ts[4] = {t.x, t.y, t.z, t.w};
            #pragma unroll
            for (int j = 0; j < 4; ++j) {
                if (ts[j] == 0.0f && mono_u(xs[j]) > tu) acc += sp_f(xs[j]);
            }
        }
    }

    // ---- block reduce + slot-hashed global accumulate ----
    #pragma unroll
    for (int off = 32; off; off >>= 1) acc += __shfl_down(acc, off);
    if (lane == 0) f_scr[wv] = acc;
    __syncthreads();
    if (tid == 0) {
        float rowsum = f_scr[0] + f_scr[1] + f_scr[2] + f_scr[3]
                     + (float)n_at * sp_f(unmono_f(tu));
        char* slot = ws + (size_t)(row & (NSLOT - 1)) * 16;
        atomicAdd((double*)slot, (double)rowsum);
        atomicAdd((float*)(slot + 8), (float)pos_total);   // exact: int-valued < 2^24
    }
}

__global__ void hardneg_finalize(const char* __restrict__ ws, float* __restrict__ out)
{
    const int l = threadIdx.x;   // 64 threads
    double n = *(const double*)(ws + (size_t)l * 16);
    float d = *(const float*)(ws + (size_t)l * 16 + 8);
    #pragma unroll
    for (int off = 32; off; off >>= 1) {
        n += __shfl_down(n, off);
        d += __shfl_down(d, off);
    }
    if (l == 0) out[0] = (d > 0.0f) ? (float)(n / (double)d) : 0.0f;
}

extern "C" void kernel_launch(void* const* d_in, const int* in_sizes, int n_in,
                              void* d_out, int out_size, void* d_ws, size_t ws_size,
                              hipStream_t stream) {
    const float* pred = (const float*)d_in[0];
    const float* target = (const float*)d_in[1];
    float* out = (float*)d_out;
    char* ws = (char*)d_ws;

    // d_ws re-poisoned to 0xAA before every timed launch -> zero the 64 slots
    hipMemsetAsync(ws, 0, NSLOT * 16, stream);

    const int nrows = in_sizes[0] / C_DIM;   // 8192
    hardneg_kernel<<<nrows, BLK, 0, stream>>>(pred, target, ws);
    hardneg_finalize<<<1, 64, 0, stream>>>(ws, out);
}